// Round 10
// baseline (431.597 us; speedup 1.0000x reference)
//
#include <hip/hip_runtime.h>

typedef _Float16 hv8 __attribute__((ext_vector_type(8)));  // 8 fp16 = 4 VGPRs MFMA A/B frag
typedef float    fv4 __attribute__((ext_vector_type(4)));  // 4 fp32 MFMA C/D frag
typedef unsigned int u32;

#define DEVI __device__ __forceinline__

static constexpr int T_   = 200;
static constexpr int ROWS = 8;      // batch rows per block (512 blocks, 2 blocks/CU)
static constexpr int WS   = 72;     // weight row stride in halfs (144 B, 16B-aligned)
static constexpr int BTOT = 4096;
static constexpr int G_   = 8;      // timesteps per barrier interval (27 barriers)

// Feed slabs carved into poolH after weight frags move to registers (offsets in halfs).
// G=8 fills the 18432-half pool exactly.
static constexpr int F1o = 0;      // [2 par][8 g][16 b][16 u] = 4096   h1 feed  w0 -> w1,w2
static constexpr int F2o = 4096;   // [2 par][8 g][16 b][32 u] = 8192   h2 feed  w1,w2 -> w3
static constexpr int XAo = 12288;  // [8 g][16 b][16 u] = 2048   w1 own h2 (u0:16)  read by w2
static constexpr int XBo = 14336;  // [8 g][16 b][16 u] = 2048   w2 own h2 (u16:32) read by w1
static constexpr int F3o = 16384;  // [8 g][16 b][16 u] = 2048   h3 (epilogue reads slot 7)
static constexpr int F_TOTAL = 18432;
// u32 views of the slabs
static constexpr int F1u = F1o / 2, F2u = F2o / 2, XAu = XAo / 2, XBu = XBo / 2, F3u = F3o / 2;

#if __has_builtin(__builtin_amdgcn_rcpf)
DEVI float frcp(float x) { return __builtin_amdgcn_rcpf(x); }
#else
DEVI float frcp(float x) { return 1.0f / x; }
#endif
DEVI float fsig(float x)  { return frcp(1.0f + __expf(-x)); }                          // inf-safe -> 0/1
DEVI float ftanh(float x) { float e = __expf(2.0f * x); return 1.0f - 2.0f * frcp(e + 1.0f); } // -> -1/1

DEVI u32 pk2h(float a, float b) {     // pack two fp32 -> fp16x2 (RNE via v_cvt_f16_f32)
    union { _Float16 h[2]; u32 u; } cv;
    cv.h[0] = (_Float16)a; cv.h[1] = (_Float16)b;
    return cv.u;
}

DEVI float ror8(float x) {            // DPP row_ror:8 -- lane nl receives lane (nl^8 within row-16)
    union { float f; int i; } cv; cv.f = x;
    cv.i = __builtin_amdgcn_mov_dpp(cv.i, 0x128, 0xf, 0xf, true);
    return cv.f;
}

union HU { hv8 h; u32 u[4]; };

// ---------------- fused 3-layer LSTM + collapsed linear head ----------------
// r9 structure (swapped-operand MFMA, lane-split activations, distributed h
// pack, 2 cells/lane, lgkm-only barrier) with G=8: EIGHT timesteps per barrier
// interval (27 barriers vs 52). r9 confirmed per-barrier overhead ~435cy
// (G2->G4 saved 29us over 50 barriers); G=8 removes 25 more. w0's x pipeline
// is now a SINGLE buffer with distributed reloads: step g reloads xc[g] for
// interval s+1 right after consuming it (full-interval vmcnt slack) -- no
// rotation movs, no interval-start load burst (w0 was the interval straggler).
// VGPR ~200 expected: still <= 256 cap for 2 waves/SIMD, occupancy unchanged
// (LDS-bound at 2 blocks/CU). Watch WRITE_SIZE for spill contamination (r5).
// Per-cell math bit-identical (absmax must stay 0.0009765625).
__global__ __launch_bounds__(256, 2) void lstm_fused(
    const float* __restrict__ xg,
    const float* __restrict__ Wih1, const float* __restrict__ Whh1,
    const float* __restrict__ bih1, const float* __restrict__ bhh1,
    const float* __restrict__ Wih2, const float* __restrict__ Whh2,
    const float* __restrict__ bih2, const float* __restrict__ bhh2,
    const float* __restrict__ Wih3, const float* __restrict__ Whh3,
    const float* __restrict__ bih3, const float* __restrict__ bhh3,
    const float* __restrict__ W_fc1, const float* __restrict__ b_fc1,
    const float* __restrict__ W_fc2, const float* __restrict__ b_fc2,
    const float* __restrict__ W_cls, const float* __restrict__ b_cls,
    float* __restrict__ outp)
{
    // poolH: weights [256 rows][WS] fp16 during prologue; feed slabs carved in afterwards
    __shared__ __align__(16) _Float16 poolH[256 * WS];       // 36864 B
    __shared__ float T2s[512];   // [32][16] = W_fc2 @ W_fc1
    __shared__ float t2vs[32];   // b_fc2 + W_fc2 @ b_fc1
    __shared__ float Msh[96];    // [16][6] collapsed head matrix
    __shared__ float vsh[6];     // collapsed head bias

    const int tid  = threadIdx.x;
    const int wid  = tid >> 6;       // 0=L1, 1/2=L2 halves, 3=L3
    const int lane = tid & 63;
    const int nl   = lane & 15;
    const int quad = lane >> 4;
    const int b0   = blockIdx.x * ROWS;

    // ---- stage weights (fp32 -> fp16) as rows [gate-row][k]; bias folded as a column ----
    // w0 (L1): k = [Wih1(0:36) | bias(36) | 0 | Whh1(48:64)]
    // w1 (L2 u0:16):  k = [Wih2(0:16) | Whh2 own u0:16 (16:32) | other u16:32 (32:48) | bias(48) | 0]
    // w2 (L2 u16:32): k = [Wih2(0:16) | Whh2 own u16:32 (16:32) | other u0:16 (32:48) | bias(48) | 0]
    // w3 (L3): k = [Wih3(0:32) | Whh3(32:48) | bias(48) | 0]
    for (int idx = tid; idx < 256 * WS; idx += 256) {
        int n = idx / WS, k = idx - n * WS;
        int w = n >> 6, r = n & 63;
        int g = r >> 4, u = r & 15;
        float v = 0.f;
        if (w == 0) {
            int row = g * 16 + u;
            if (k < 36)       v = Wih1[row * 36 + k];
            else if (k == 36) v = bih1[row] + bhh1[row];
            else if (k >= 48 && k < 64) v = Whh1[row * 16 + (k - 48)];
        } else if (w <= 2) {
            int row = g * 32 + (w - 1) * 16 + u;
            if (k < 16)       v = Wih2[row * 16 + k];
            else if (k < 48)  {
                int kk = k - 16;   // 0..31 = [own 0..15 | other 16..31]
                int uu = (w == 1) ? kk : ((kk < 16) ? kk + 16 : kk - 16);
                v = Whh2[row * 32 + uu];
            }
            else if (k == 48) v = bih2[row] + bhh2[row];
        } else {
            int row = g * 16 + u;
            if (k < 32)       v = Wih3[row * 32 + k];
            else if (k < 48)  v = Whh3[row * 16 + (k - 32)];
            else if (k == 48) v = bih3[row] + bhh3[row];
        }
        poolH[idx] = (_Float16)v;
    }
    // head: T2 = W_fc2 @ W_fc1 (fp32; 24KB weights, L2-resident)
    for (int idx = tid; idx < 512; idx += 256) {
        int b = idx >> 4, u = idx & 15;
        float acc = 0.f;
        for (int a = 0; a < 128; ++a) acc += W_fc2[b * 128 + a] * W_fc1[a * 16 + u];
        T2s[idx] = acc;
    }
    if (tid < 32) {
        float acc = b_fc2[tid];
        for (int a = 0; a < 128; ++a) acc += W_fc2[tid * 128 + a] * b_fc1[a];
        t2vs[tid] = acc;
    }
    __syncthreads();

    // ---- per-wave register-resident weight A-frags: lane holds W[mt*16+nl][kt*32+quad*8+j] ----
    hv8 Wf[2][4];
    #pragma unroll
    for (int kt = 0; kt < 2; ++kt)
        #pragma unroll
        for (int mt = 0; mt < 4; ++mt)
            Wf[kt][mt] = *(const hv8*)&poolH[(wid * 64 + mt * 16 + nl) * WS + kt * 32 + quad * 8];
    // collapsed head: M[u][j] = sum_b Wc[j][b]*T2[b][u];  v[j] = bc[j] + sum_b Wc[j][b]*t2v[b]
    if (tid < 96) {
        int u = tid / 6, j = tid - (tid / 6) * 6;
        float acc = 0.f;
        for (int b = 0; b < 32; ++b) acc += W_cls[j * 32 + b] * T2s[b * 16 + u];
        Msh[u * 6 + j] = acc;
    }
    if (tid < 6) {
        float acc = b_cls[tid];
        for (int b = 0; b < 32; ++b) acc += W_cls[tid * 32 + b] * t2vs[b];
        vsh[tid] = acc;
    }
    __syncthreads();   // weights now in registers; pool reusable

    // ---- zero feed slabs (h == 0 for pre-start reads) + prologue x loads (t=0..7) ----
    for (int idx = tid; idx < F_TOTAL; idx += 256) poolH[idx] = (_Float16)0.f;

    fv4 xc[G_][3];                     // w0 only: single-buffer x pipeline (reload-after-use)
    const float* xb = xg;
    if (wid == 0) {
        // lanes nl >= ROWS duplicate the last real row (identical addrs coalesce; r5/r6 lesson)
        int xr = b0 + (nl < ROWS ? nl : ROWS - 1);
        if (xr > BTOT - 1) xr = BTOT - 1;
        xb = xg + (size_t)xr * T_ * 36;
        #pragma unroll
        for (int g = 0; g < G_; ++g) {
            xc[g][0] = *(const fv4*)(xb + g * 36 + quad * 8);
            xc[g][1] = *(const fv4*)(xb + g * 36 + quad * 8 + 4);
            xc[g][2] = *(const fv4*)(xb + g * 36 + 32);
        }
    }
    __syncthreads();

    // Distributed h pack: one u32 per lane. Lanes nl<8: units {q*4+0,1}; lanes
    // nl>=8: units {q*4+2,3}; batch nl&7.
    u32 pkAB = 0;
    float c_st[2] = {0.f, 0.f};             // cell state: 2 cells/lane (role-dependent rows)
    const bool loRole = (nl < 8);
    const int  nlb = nl & 7, ro = nl >> 3;
    // bpermute byte indices for B-frag assembly (u[0..3] = unit pairs of the k-slice):
    const int iA = ((quad & 1) * 32 + nlb) * 4;   // pk01 of group (quad&1)*2
    const int iB = iA + 32;                       // pk23 of group (quad&1)*2
    const int iC = iA + 64;                       // pk01 of group (quad&1)*2+1
    const int iD = iA + 96;                       // pk23 of group (quad&1)*2+1
    const u32 BIAS1 = 0x00003C00u;          // fp16 1.0 in low half

    const int NI = T_ / G_ + 2;   // 27 barrier intervals, 8 timesteps each
    for (int s = 0; s < NI; ++s) {
        const int pp = (s - 1) & 1, wp = s & 1;
        bool act;
        if (wid == 0)      act = (s < T_ / G_);             // L1: t=8s..8s+7
        else if (wid <= 2) act = (s >= 1 && s <= T_ / G_);  // L2: t=8s-8..8s-1
        else               act = (s >= 2);                  // L3: t=8s-16..8s-9

        HU pf[G_], sibIn;   // per-interval prefetches (barrier-protected, prev-interval data)
        if (act) {
            if (wid == 1 || wid == 2) {
                #pragma unroll
                for (int g = 0; g < G_; ++g)
                    pf[g].h = *(const hv8*)&poolH[F1o + ((pp * G_ + g) * 16 + nl) * 16 + (quad & 1) * 8];
                // other-half h2 for g0: sibling's slot-7 write from PREVIOUS interval.
                const int sibX = (wid == 1) ? XBo : XAo;
                sibIn.h = *(const hv8*)&poolH[sibX + (7 * 16 + nl) * 16 + (quad & 1) * 8];
            } else if (wid == 3) {
                #pragma unroll
                for (int g = 0; g < G_; ++g)
                    pf[g].h = *(const hv8*)&poolH[F2o + ((pp * G_ + g) * 16 + nl) * 32 + quad * 8];
            }

            #pragma unroll
            for (int g = 0; g < G_; ++g) {
                // recurrence transpose: 4 bpermutes of the distributed h pack
                u32 sA = (u32)__builtin_amdgcn_ds_bpermute(iA, (int)pkAB);
                u32 sB = (u32)__builtin_amdgcn_ds_bpermute(iB, (int)pkAB);
                u32 sC = (u32)__builtin_amdgcn_ds_bpermute(iC, (int)pkAB);
                u32 sD = (u32)__builtin_amdgcn_ds_bpermute(iD, (int)pkAB);

                HU bk0, bk1;
                if (wid == 0) {
                    // kt0: x feats 0..31 (regs); kt1: q<2 feats 32..35+bias, q>=2 own h1 (shuffles)
                    bk0.u[0] = pk2h(xc[g][0][0], xc[g][0][1]);
                    bk0.u[1] = pk2h(xc[g][0][2], xc[g][0][3]);
                    bk0.u[2] = pk2h(xc[g][1][0], xc[g][1][1]);
                    bk0.u[3] = pk2h(xc[g][1][2], xc[g][1][3]);
                    if (quad >= 2) { bk1.u[0]=sA; bk1.u[1]=sB; bk1.u[2]=sC; bk1.u[3]=sD; }
                    else {
                        bk1.u[0] = pk2h(xc[g][2][0], xc[g][2][1]);
                        bk1.u[1] = pk2h(xc[g][2][2], xc[g][2][3]);
                        bk1.u[2] = BIAS1; bk1.u[3] = 0u;    // k36 bias; k37..39 zero-weight cols
                    }
                } else if (wid <= 2) {
                    // kt0: q<2 h1 feed, q>=2 own h2 (shuffles); kt1: q<2 other h2, q>=2 bias/zero-cols
                    if (quad < 2) bk0 = pf[g];
                    else { bk0.u[0]=sA; bk0.u[1]=sB; bk0.u[2]=sC; bk0.u[3]=sD; }
                    if (quad < 2) bk1 = sibIn;
                    else { bk1.u[0]=BIAS1; bk1.u[1]=0u; bk1.u[2]=0u; bk1.u[3]=0u; }
                } else {
                    // kt0: h2 feed (all quads); kt1: q<2 own h3 (shuffles), q>=2 bias/zero-cols
                    bk0 = pf[g];
                    if (quad < 2) { bk1.u[0]=sA; bk1.u[1]=sB; bk1.u[2]=sC; bk1.u[3]=sD; }
                    else { bk1.u[0]=BIAS1; bk1.u[1]=0u; bk1.u[2]=0u; bk1.u[3]=0u; }
                }

                fv4 C[4] = {(fv4){0,0,0,0}, (fv4){0,0,0,0}, (fv4){0,0,0,0}, (fv4){0,0,0,0}};
                #pragma unroll
                for (int mt = 0; mt < 4; ++mt) C[mt] = __builtin_amdgcn_mfma_f32_16x16x32_f16(Wf[0][mt], bk0.h, C[mt], 0, 0, 0);
                #pragma unroll
                for (int mt = 0; mt < 4; ++mt) C[mt] = __builtin_amdgcn_mfma_f32_16x16x32_f16(Wf[1][mt], bk1.h, C[mt], 0, 0, 0);

                // ---- split activations across lane halves: DPP moves r=2,3 to hi lanes ----
                float e0[4], e1[4];
                #pragma unroll
                for (int mt = 0; mt < 4; ++mt) {
                    float t2 = ror8(C[mt][2]);
                    float t3 = ror8(C[mt][3]);
                    e0[mt] = loRole ? C[mt][0] : t2;
                    e1[mt] = loRole ? C[mt][1] : t3;
                }
                float h0, h1;
                {
                    float gi = fsig(e0[0]), gf = fsig(e0[1]), gg = ftanh(e0[2]), go = fsig(e0[3]);
                    float c = gf * c_st[0] + gi * gg; c_st[0] = c; h0 = go * ftanh(c);
                }
                {
                    float gi = fsig(e1[0]), gf = fsig(e1[1]), gg = ftanh(e1[2]), go = fsig(e1[3]);
                    float c = gf * c_st[1] + gi * gg; c_st[1] = c; h1 = go * ftanh(c);
                }
                pkAB = pk2h(h0, h1);

                // feed writes (off critical path): ONE u32 per lane into [batch][unit] slabs
                u32* pb = (u32*)poolH;
                if (wid == 0) {
                    pb[F1u + ((wp * G_ + g) * 16 + nlb) * 8 + quad * 2 + ro] = pkAB;
                    // distributed x reload: refill the just-consumed slot for interval s+1
                    int t = G_ * (s + 1) + g;
                    if (t < T_) {
                        xc[g][0] = *(const fv4*)(xb + t * 36 + quad * 8);
                        xc[g][1] = *(const fv4*)(xb + t * 36 + quad * 8 + 4);
                        xc[g][2] = *(const fv4*)(xb + t * 36 + 32);
                    }
                } else if (wid <= 2) {
                    const int ownXu = (wid == 1) ? XAu : XBu;
                    pb[ownXu + (g * 16 + nlb) * 8 + quad * 2 + ro] = pkAB;
                    const int ub2 = (wid == 1) ? 0 : 8;
                    pb[F2u + ((wp * G_ + g) * 16 + nlb) * 16 + ub2 + quad * 2 + ro] = pkAB;
                    if (g < G_ - 1) {   // sibling's slot-g write for our step g+1 (read after own
                                        // writes; bounded-skew, same placement as r3..r9)
                        const int sibX = (wid == 1) ? XBo : XAo;
                        sibIn.h = *(const hv8*)&poolH[sibX + (g * 16 + nl) * 16 + (quad & 1) * 8];
                    }
                } else {
                    pb[F3u + (g * 16 + nlb) * 8 + quad * 2 + ro] = pkAB;
                }
            }
        }
        // LDS-visibility barrier only (r8: vmcnt drain removal neutral; keep the cheap form)
        asm volatile("s_waitcnt lgkmcnt(0)\n\ts_barrier" ::: "memory");
    }

    // ---- epilogue: out[b][j] = h3(T-1) . M[:,j] + v[j]   (t=199 -> F3 slot 7) ----
    if (tid < ROWS * 6) {
        int row = tid / 6, j = tid - (tid / 6) * 6;
        float acc = vsh[j];
        const int hb = F3o + 7 * 256 + row * 16;
        #pragma unroll
        for (int u = 0; u < 16; ++u)
            acc += (float)poolH[hb + u] * Msh[u * 6 + j];
        outp[(b0 + row) * 6 + j] = acc;
    }
}

extern "C" void kernel_launch(void* const* d_in, const int* in_sizes, int n_in,
                              void* d_out, int out_size, void* d_ws, size_t ws_size,
                              hipStream_t stream) {
    const float* x     = (const float*)d_in[0];
    const float* Wih1  = (const float*)d_in[1];
    const float* Whh1  = (const float*)d_in[2];
    const float* bih1  = (const float*)d_in[3];
    const float* bhh1  = (const float*)d_in[4];
    const float* Wih2  = (const float*)d_in[5];
    const float* Whh2  = (const float*)d_in[6];
    const float* bih2  = (const float*)d_in[7];
    const float* bhh2  = (const float*)d_in[8];
    const float* Wih3  = (const float*)d_in[9];
    const float* Whh3  = (const float*)d_in[10];
    const float* bih3  = (const float*)d_in[11];
    const float* bhh3  = (const float*)d_in[12];
    const float* W_fc1 = (const float*)d_in[13];
    const float* b_fc1 = (const float*)d_in[14];
    const float* W_fc2 = (const float*)d_in[15];
    const float* b_fc2 = (const float*)d_in[16];
    const float* W_cls = (const float*)d_in[17];
    const float* b_cls = (const float*)d_in[18];

    lstm_fused<<<512, 256, 0, stream>>>(x,
        Wih1, Whh1, bih1, bhh1,
        Wih2, Whh2, bih2, bhh2,
        Wih3, Whh3, bih3, bhh3,
        W_fc1, b_fc1, W_fc2, b_fc2, W_cls, b_cls,
        (float*)d_out);
}

// Round 11
// 364.147 us; speedup vs baseline: 1.1852x; 1.1852x over previous
//
#include <hip/hip_runtime.h>

typedef _Float16 hv8 __attribute__((ext_vector_type(8)));  // 8 fp16 = 4 VGPRs MFMA A/B frag
typedef float    fv4 __attribute__((ext_vector_type(4)));  // 4 fp32 MFMA C/D frag
typedef unsigned int u32;

#define DEVI __device__ __forceinline__

static constexpr int T_   = 200;
static constexpr int ROWS = 8;      // batch rows per block (512 blocks, 2 blocks/CU)
static constexpr int WS   = 72;     // weight row stride in halfs (144 B, 16B-aligned)
static constexpr int BTOT = 4096;
static constexpr int G_   = 4;      // timesteps per barrier interval (52 barriers; r10: G=8 regressed)

// Feed slabs carved into poolH after weight frags move to registers (offsets in halfs).
static constexpr int F1o = 0;      // [2 par][4 g][16 b][16 u]  h1 feed  w0 -> w1,w2
static constexpr int F2o = 2048;   // [2 par][4 g][16 b][32 u]  h2 feed  w1,w2 -> w3
static constexpr int XAo = 6144;   // [4 g][16 b][16 u]  w1 own h2 (u0:16)  read by w2
static constexpr int XBo = 7168;   // [4 g][16 b][16 u]  w2 own h2 (u16:32) read by w1
static constexpr int F3o = 8192;   // [4 g][16 b][16 u]  h3 (epilogue reads slot 3)
static constexpr int F_TOTAL = 9216;   // <= 18432 halfs of the weight pool
// u32 views of the slabs
static constexpr int F1u = F1o / 2, F2u = F2o / 2, XAu = XAo / 2, XBu = XBo / 2, F3u = F3o / 2;

#if __has_builtin(__builtin_amdgcn_rcpf)
DEVI float frcp(float x) { return __builtin_amdgcn_rcpf(x); }
#else
DEVI float frcp(float x) { return 1.0f / x; }
#endif

DEVI u32 pk2h(float a, float b) {     // pack two fp32 -> fp16x2 (RNE via v_cvt_f16_f32)
    union { _Float16 h[2]; u32 u; } cv;
    cv.h[0] = (_Float16)a; cv.h[1] = (_Float16)b;
    return cv.u;
}

DEVI float ror8(float x) {            // DPP row_ror:8 -- lane nl receives lane (nl+8)&15 within row-16
    union { float f; int i; } cv; cv.f = x;
    cv.i = __builtin_amdgcn_mov_dpp(cv.i, 0x128, 0xf, 0xf, true);
    return cv.f;
}

union HU { hv8 h; u32 u[4]; };

// ---------------- fused 3-layer LSTM + collapsed linear head ----------------
// r9 structure (swapped-operand MFMA, lane-split activations, distributed h
// pack, 2 cells/lane, G=4, lgkm-only barrier) + COMBINED-RCP activations:
//   gi*gg = (e^2g - 1) * rcp((e^2g + 1)(1 + e^-i))
//   h     = (e^2c - 1) * rcp((e^2c + 1)(1 + e^-o))
// merges the tanh/sigmoid rcps pairwise: 10 -> 8 trans per cell (trans pipe
// ~320cy/step/SIMD was the largest single term in the r9 ledger). Math is
// identical up to ~1ulp fp32 reassociation; overflow only at |arg|>~44sigma
// (unreachable for ~1sigma pre-activations). r10 lesson: G=8 + distributed
// x reload regressed (loop-carried vmcnt conservatism / I-cache); G=4 kept.
__global__ __launch_bounds__(256, 2) void lstm_fused(
    const float* __restrict__ xg,
    const float* __restrict__ Wih1, const float* __restrict__ Whh1,
    const float* __restrict__ bih1, const float* __restrict__ bhh1,
    const float* __restrict__ Wih2, const float* __restrict__ Whh2,
    const float* __restrict__ bih2, const float* __restrict__ bhh2,
    const float* __restrict__ Wih3, const float* __restrict__ Whh3,
    const float* __restrict__ bih3, const float* __restrict__ bhh3,
    const float* __restrict__ W_fc1, const float* __restrict__ b_fc1,
    const float* __restrict__ W_fc2, const float* __restrict__ b_fc2,
    const float* __restrict__ W_cls, const float* __restrict__ b_cls,
    float* __restrict__ outp)
{
    // poolH: weights [256 rows][WS] fp16 during prologue; feed slabs carved in afterwards
    __shared__ __align__(16) _Float16 poolH[256 * WS];       // 36864 B
    __shared__ float T2s[512];   // [32][16] = W_fc2 @ W_fc1
    __shared__ float t2vs[32];   // b_fc2 + W_fc2 @ b_fc1
    __shared__ float Msh[96];    // [16][6] collapsed head matrix
    __shared__ float vsh[6];     // collapsed head bias

    const int tid  = threadIdx.x;
    const int wid  = tid >> 6;       // 0=L1, 1/2=L2 halves, 3=L3
    const int lane = tid & 63;
    const int nl   = lane & 15;
    const int quad = lane >> 4;
    const int b0   = blockIdx.x * ROWS;

    // ---- stage weights (fp32 -> fp16) as rows [gate-row][k]; bias folded as a column ----
    // w0 (L1): k = [Wih1(0:36) | bias(36) | 0 | Whh1(48:64)]
    // w1 (L2 u0:16):  k = [Wih2(0:16) | Whh2 own u0:16 (16:32) | other u16:32 (32:48) | bias(48) | 0]
    // w2 (L2 u16:32): k = [Wih2(0:16) | Whh2 own u16:32 (16:32) | other u0:16 (32:48) | bias(48) | 0]
    // w3 (L3): k = [Wih3(0:32) | Whh3(32:48) | bias(48) | 0]
    for (int idx = tid; idx < 256 * WS; idx += 256) {
        int n = idx / WS, k = idx - n * WS;
        int w = n >> 6, r = n & 63;
        int g = r >> 4, u = r & 15;
        float v = 0.f;
        if (w == 0) {
            int row = g * 16 + u;
            if (k < 36)       v = Wih1[row * 36 + k];
            else if (k == 36) v = bih1[row] + bhh1[row];
            else if (k >= 48 && k < 64) v = Whh1[row * 16 + (k - 48)];
        } else if (w <= 2) {
            int row = g * 32 + (w - 1) * 16 + u;
            if (k < 16)       v = Wih2[row * 16 + k];
            else if (k < 48)  {
                int kk = k - 16;   // 0..31 = [own 0..15 | other 16..31]
                int uu = (w == 1) ? kk : ((kk < 16) ? kk + 16 : kk - 16);
                v = Whh2[row * 32 + uu];
            }
            else if (k == 48) v = bih2[row] + bhh2[row];
        } else {
            int row = g * 16 + u;
            if (k < 32)       v = Wih3[row * 32 + k];
            else if (k < 48)  v = Whh3[row * 16 + (k - 32)];
            else if (k == 48) v = bih3[row] + bhh3[row];
        }
        poolH[idx] = (_Float16)v;
    }
    // head: T2 = W_fc2 @ W_fc1 (fp32; 24KB weights, L2-resident)
    for (int idx = tid; idx < 512; idx += 256) {
        int b = idx >> 4, u = idx & 15;
        float acc = 0.f;
        for (int a = 0; a < 128; ++a) acc += W_fc2[b * 128 + a] * W_fc1[a * 16 + u];
        T2s[idx] = acc;
    }
    if (tid < 32) {
        float acc = b_fc2[tid];
        for (int a = 0; a < 128; ++a) acc += W_fc2[tid * 128 + a] * b_fc1[a];
        t2vs[tid] = acc;
    }
    __syncthreads();

    // ---- per-wave register-resident weight A-frags: lane holds W[mt*16+nl][kt*32+quad*8+j] ----
    hv8 Wf[2][4];
    #pragma unroll
    for (int kt = 0; kt < 2; ++kt)
        #pragma unroll
        for (int mt = 0; mt < 4; ++mt)
            Wf[kt][mt] = *(const hv8*)&poolH[(wid * 64 + mt * 16 + nl) * WS + kt * 32 + quad * 8];
    // collapsed head: M[u][j] = sum_b Wc[j][b]*T2[b][u];  v[j] = bc[j] + sum_b Wc[j][b]*t2v[b]
    if (tid < 96) {
        int u = tid / 6, j = tid - (tid / 6) * 6;
        float acc = 0.f;
        for (int b = 0; b < 32; ++b) acc += W_cls[j * 32 + b] * T2s[b * 16 + u];
        Msh[u * 6 + j] = acc;
    }
    if (tid < 6) {
        float acc = b_cls[tid];
        for (int b = 0; b < 32; ++b) acc += W_cls[tid * 32 + b] * t2vs[b];
        vsh[tid] = acc;
    }
    __syncthreads();   // weights now in registers; pool reusable

    // ---- zero feed slabs (h == 0 for pre-start reads) + prologue x loads (t=0..7) ----
    for (int idx = tid; idx < F_TOTAL; idx += 256) poolH[idx] = (_Float16)0.f;

    fv4 xc[G_][3], xn[G_][3];          // w0 only: [g][chunk] feats q*8..+3, +4..+7, 32..35
    const float* xb = xg;
    if (wid == 0) {
        // lanes nl >= ROWS duplicate the last real row (identical addrs coalesce; r5/r6 lesson)
        int xr = b0 + (nl < ROWS ? nl : ROWS - 1);
        if (xr > BTOT - 1) xr = BTOT - 1;
        xb = xg + (size_t)xr * T_ * 36;
        #pragma unroll
        for (int g = 0; g < G_; ++g) {
            xn[g][0] = *(const fv4*)(xb + g * 36 + quad * 8);
            xn[g][1] = *(const fv4*)(xb + g * 36 + quad * 8 + 4);
            xn[g][2] = *(const fv4*)(xb + g * 36 + 32);
        }
    }
    __syncthreads();

    // Distributed h pack: one u32 per lane. Lanes nl<8: units {q*4+0,1}; lanes
    // nl>=8: units {q*4+2,3}; batch nl&7.
    u32 pkAB = 0;
    float c_st[2] = {0.f, 0.f};             // cell state: 2 cells/lane (role-dependent rows)
    const bool loRole = (nl < 8);
    const int  nlb = nl & 7, ro = nl >> 3;
    // bpermute byte indices for B-frag assembly (u[0..3] = unit pairs of the k-slice):
    const int iA = ((quad & 1) * 32 + nlb) * 4;   // pk01 of group (quad&1)*2
    const int iB = iA + 32;                       // pk23 of group (quad&1)*2
    const int iC = iA + 64;                       // pk01 of group (quad&1)*2+1
    const int iD = iA + 96;                       // pk23 of group (quad&1)*2+1
    const u32 BIAS1 = 0x00003C00u;          // fp16 1.0 in low half

    const int NI = T_ / G_ + 2;   // 52 barrier intervals, 4 timesteps each
    for (int s = 0; s < NI; ++s) {
        const int pp = (s - 1) & 1, wp = s & 1;
        bool act;
        if (wid == 0)      act = (s < T_ / G_);             // L1: t=4s..4s+3
        else if (wid <= 2) act = (s >= 1 && s <= T_ / G_);  // L2: t=4s-4..4s-1
        else               act = (s >= 2);                  // L3: t=4s-8..4s-5

        HU pf[G_], sibIn;   // per-interval prefetches (barrier-protected, prev-interval data)
        if (act) {
            if (wid == 0) {
                #pragma unroll
                for (int g = 0; g < G_; ++g) { xc[g][0]=xn[g][0]; xc[g][1]=xn[g][1]; xc[g][2]=xn[g][2]; }
                #pragma unroll
                for (int g = 0; g < G_; ++g) {
                    int t = G_ * s + G_ + g;
                    if (t < T_) {
                        xn[g][0] = *(const fv4*)(xb + t * 36 + quad * 8);
                        xn[g][1] = *(const fv4*)(xb + t * 36 + quad * 8 + 4);
                        xn[g][2] = *(const fv4*)(xb + t * 36 + 32);
                    }
                }
            } else if (wid <= 2) {
                #pragma unroll
                for (int g = 0; g < G_; ++g)
                    pf[g].h = *(const hv8*)&poolH[F1o + ((pp * G_ + g) * 16 + nl) * 16 + (quad & 1) * 8];
                // other-half h2 for g0: sibling's slot-3 write from PREVIOUS interval.
                const int sibX = (wid == 1) ? XBo : XAo;
                sibIn.h = *(const hv8*)&poolH[sibX + (3 * 16 + nl) * 16 + (quad & 1) * 8];
            } else {
                #pragma unroll
                for (int g = 0; g < G_; ++g)
                    pf[g].h = *(const hv8*)&poolH[F2o + ((pp * G_ + g) * 16 + nl) * 32 + quad * 8];
            }

            #pragma unroll
            for (int g = 0; g < G_; ++g) {
                // recurrence transpose: 4 bpermutes of the distributed h pack
                u32 sA = (u32)__builtin_amdgcn_ds_bpermute(iA, (int)pkAB);
                u32 sB = (u32)__builtin_amdgcn_ds_bpermute(iB, (int)pkAB);
                u32 sC = (u32)__builtin_amdgcn_ds_bpermute(iC, (int)pkAB);
                u32 sD = (u32)__builtin_amdgcn_ds_bpermute(iD, (int)pkAB);

                HU bk0, bk1;
                if (wid == 0) {
                    // kt0: x feats 0..31 (regs); kt1: q<2 feats 32..35+bias, q>=2 own h1 (shuffles)
                    bk0.u[0] = pk2h(xc[g][0][0], xc[g][0][1]);
                    bk0.u[1] = pk2h(xc[g][0][2], xc[g][0][3]);
                    bk0.u[2] = pk2h(xc[g][1][0], xc[g][1][1]);
                    bk0.u[3] = pk2h(xc[g][1][2], xc[g][1][3]);
                    if (quad >= 2) { bk1.u[0]=sA; bk1.u[1]=sB; bk1.u[2]=sC; bk1.u[3]=sD; }
                    else {
                        bk1.u[0] = pk2h(xc[g][2][0], xc[g][2][1]);
                        bk1.u[1] = pk2h(xc[g][2][2], xc[g][2][3]);
                        bk1.u[2] = BIAS1; bk1.u[3] = 0u;    // k36 bias; k37..39 zero-weight cols
                    }
                } else if (wid <= 2) {
                    // kt0: q<2 h1 feed, q>=2 own h2 (shuffles); kt1: q<2 other h2, q>=2 bias/zero-cols
                    if (quad < 2) bk0 = pf[g];
                    else { bk0.u[0]=sA; bk0.u[1]=sB; bk0.u[2]=sC; bk0.u[3]=sD; }
                    if (quad < 2) bk1 = sibIn;
                    else { bk1.u[0]=BIAS1; bk1.u[1]=0u; bk1.u[2]=0u; bk1.u[3]=0u; }
                } else {
                    // kt0: h2 feed (all quads); kt1: q<2 own h3 (shuffles), q>=2 bias/zero-cols
                    bk0 = pf[g];
                    if (quad < 2) { bk1.u[0]=sA; bk1.u[1]=sB; bk1.u[2]=sC; bk1.u[3]=sD; }
                    else { bk1.u[0]=BIAS1; bk1.u[1]=0u; bk1.u[2]=0u; bk1.u[3]=0u; }
                }

                fv4 C[4] = {(fv4){0,0,0,0}, (fv4){0,0,0,0}, (fv4){0,0,0,0}, (fv4){0,0,0,0}};
                #pragma unroll
                for (int mt = 0; mt < 4; ++mt) C[mt] = __builtin_amdgcn_mfma_f32_16x16x32_f16(Wf[0][mt], bk0.h, C[mt], 0, 0, 0);
                #pragma unroll
                for (int mt = 0; mt < 4; ++mt) C[mt] = __builtin_amdgcn_mfma_f32_16x16x32_f16(Wf[1][mt], bk1.h, C[mt], 0, 0, 0);

                // ---- split activations across lane halves: DPP moves r=2,3 to hi lanes ----
                float e0[4], e1[4];
                #pragma unroll
                for (int mt = 0; mt < 4; ++mt) {
                    float t2 = ror8(C[mt][2]);
                    float t3 = ror8(C[mt][3]);
                    e0[mt] = loRole ? C[mt][0] : t2;
                    e1[mt] = loRole ? C[mt][1] : t3;
                }
                // combined-rcp gates: 8 trans/cell (5 exp + 3 rcp), vs 10 with
                // separate sigmoid/tanh rcps. Same math, ~1ulp fp32 difference.
                float h0, h1;
                {
                    float ei = __expf(-e0[0]), ef = __expf(-e0[1]);
                    float eg = __expf(2.0f * e0[2]), eo = __expf(-e0[3]);
                    float gf = frcp(1.0f + ef);
                    float gig = (eg - 1.0f) * frcp((eg + 1.0f) * (1.0f + ei));
                    float c = gf * c_st[0] + gig; c_st[0] = c;
                    float ec = __expf(2.0f * c);
                    h0 = (ec - 1.0f) * frcp((ec + 1.0f) * (1.0f + eo));
                }
                {
                    float ei = __expf(-e1[0]), ef = __expf(-e1[1]);
                    float eg = __expf(2.0f * e1[2]), eo = __expf(-e1[3]);
                    float gf = frcp(1.0f + ef);
                    float gig = (eg - 1.0f) * frcp((eg + 1.0f) * (1.0f + ei));
                    float c = gf * c_st[1] + gig; c_st[1] = c;
                    float ec = __expf(2.0f * c);
                    h1 = (ec - 1.0f) * frcp((ec + 1.0f) * (1.0f + eo));
                }
                pkAB = pk2h(h0, h1);

                // feed writes (off critical path): ONE u32 per lane into [batch][unit] slabs
                u32* pb = (u32*)poolH;
                if (wid == 0) {
                    pb[F1u + ((wp * G_ + g) * 16 + nlb) * 8 + quad * 2 + ro] = pkAB;
                } else if (wid <= 2) {
                    const int ownXu = (wid == 1) ? XAu : XBu;
                    pb[ownXu + (g * 16 + nlb) * 8 + quad * 2 + ro] = pkAB;
                    const int ub2 = (wid == 1) ? 0 : 8;
                    pb[F2u + ((wp * G_ + g) * 16 + nlb) * 16 + ub2 + quad * 2 + ro] = pkAB;
                    if (g < G_ - 1) {   // sibling's slot-g write for our step g+1 (read after own
                                        // writes; bounded-skew, same placement as r3..r9)
                        const int sibX = (wid == 1) ? XBo : XAo;
                        sibIn.h = *(const hv8*)&poolH[sibX + (g * 16 + nl) * 16 + (quad & 1) * 8];
                    }
                } else {
                    pb[F3u + (g * 16 + nlb) * 8 + quad * 2 + ro] = pkAB;
                }
            }
        }
        // LDS-visibility barrier only (r8: vmcnt drain removal neutral; keep the cheap form)
        asm volatile("s_waitcnt lgkmcnt(0)\n\ts_barrier" ::: "memory");
    }

    // ---- epilogue: out[b][j] = h3(T-1) . M[:,j] + v[j]   (t=199 -> F3 slot 3) ----
    if (tid < ROWS * 6) {
        int row = tid / 6, j = tid - (tid / 6) * 6;
        float acc = vsh[j];
        const int hb = F3o + 3 * 256 + row * 16;
        #pragma unroll
        for (int u = 0; u < 16; ++u)
            acc += (float)poolH[hb + u] * Msh[u * 6 + j];
        outp[(b0 + row) * 6 + j] = acc;
    }
}

extern "C" void kernel_launch(void* const* d_in, const int* in_sizes, int n_in,
                              void* d_out, int out_size, void* d_ws, size_t ws_size,
                              hipStream_t stream) {
    const float* x     = (const float*)d_in[0];
    const float* Wih1  = (const float*)d_in[1];
    const float* Whh1  = (const float*)d_in[2];
    const float* bih1  = (const float*)d_in[3];
    const float* bhh1  = (const float*)d_in[4];
    const float* Wih2  = (const float*)d_in[5];
    const float* Whh2  = (const float*)d_in[6];
    const float* bih2  = (const float*)d_in[7];
    const float* bhh2  = (const float*)d_in[8];
    const float* Wih3  = (const float*)d_in[9];
    const float* Whh3  = (const float*)d_in[10];
    const float* bih3  = (const float*)d_in[11];
    const float* bhh3  = (const float*)d_in[12];
    const float* W_fc1 = (const float*)d_in[13];
    const float* b_fc1 = (const float*)d_in[14];
    const float* W_fc2 = (const float*)d_in[15];
    const float* b_fc2 = (const float*)d_in[16];
    const float* W_cls = (const float*)d_in[17];
    const float* b_cls = (const float*)d_in[18];

    lstm_fused<<<512, 256, 0, stream>>>(x,
        Wih1, Whh1, bih1, bhh1,
        Wih2, Whh2, bih2, bhh2,
        Wih3, Whh3, bih3, bhh3,
        W_fc1, b_fc1, W_fc2, b_fc2, W_cls, b_cls,
        (float*)d_out);
}